// Round 2
// baseline (8477.939 us; speedup 1.0000x reference)
//
#include <hip/hip_runtime.h>
#include <math.h>

// Problem constants: B=1, T=2048, D=1024, H=16, HD=64, STRIDE=8, Tg=256.
// Output 0: weighted [2048][1024]
// Output 1: combined [3][2048][2048] = (s0+s1+s3) * {linear_w, sparse_w, quantum_w}
//   (reference's broadcasting makes wstack*wsel rank-5; sum(axis=1) sums the
//    strategy-prob axis, leaving the 3 attention planes each scaled by S.)
#define D_MODEL 1024

// ---------------------------------------------------------------------------
// GEMM: C[M,N] (+)= scale * (X[M,K] @ W[N,K]^T + bias)
// ---------------------------------------------------------------------------
__global__ __launch_bounds__(256) void gemm_xwt(
    const float* __restrict__ X, int xrstride,
    const float* __restrict__ W, int wrstride,
    const float* __restrict__ bias,
    float* __restrict__ C, int M, int N, int K,
    const float* __restrict__ sptr, int sidx, int accum)
{
    __shared__ float Xs[16][68];
    __shared__ float Ws[16][68];
    const int tid = threadIdx.x;
    const int m0 = blockIdx.x * 64, n0 = blockIdx.y * 64;
    const int ty = tid >> 4, tx = tid & 15;
    float acc[4][4] = {};
    for (int k0 = 0; k0 < K; k0 += 16) {
        __syncthreads();
#pragma unroll
        for (int i = 0; i < 4; ++i) {
            int li = tid + i * 256;
            int r = li >> 4, kk = li & 15;
            Xs[kk][r] = X[(size_t)(m0 + r) * xrstride + k0 + kk];
            Ws[kk][r] = W[(size_t)(n0 + r) * wrstride + k0 + kk];
        }
        __syncthreads();
#pragma unroll
        for (int kk = 0; kk < 16; ++kk) {
            float4 a4 = *(const float4*)&Xs[kk][ty * 4];
            float4 b4 = *(const float4*)&Ws[kk][tx * 4];
            float av[4] = {a4.x, a4.y, a4.z, a4.w};
            float bv[4] = {b4.x, b4.y, b4.z, b4.w};
#pragma unroll
            for (int i = 0; i < 4; ++i)
#pragma unroll
                for (int j = 0; j < 4; ++j)
                    acc[i][j] += av[i] * bv[j];
        }
    }
    const float s = (sptr != nullptr) ? sptr[sidx] : 1.0f;
#pragma unroll
    for (int i = 0; i < 4; ++i) {
        const size_t row = (size_t)(m0 + ty * 4 + i) * N;
#pragma unroll
        for (int j = 0; j < 4; ++j) {
            const int col = n0 + tx * 4 + j;
            float v = acc[i][j] + (bias ? bias[col] : 0.0f);
            if (accum) C[row + col] += s * v;
            else       C[row + col]  = s * v;
        }
    }
}

// ---------------------------------------------------------------------------
// Per-head score multiplier alpha:
//   amode 0: 1.0
//   amode 1: sparsity mask  (sigmoid(x) > 0.5  <=>  x > 0)
//   amode 2: gate = sigmoid(ent_gate[h,0,0])   (stride 4)
// ---------------------------------------------------------------------------
__device__ __forceinline__ float head_alpha(const float* ap, int amode, int h) {
    if (amode == 1) return (ap[h] > 0.0f) ? 1.0f : 0.0f;
    if (amode == 2) return 1.0f / (1.0f + __expf(-ap[h * 4]));
    return 1.0f;
}

// ---------------------------------------------------------------------------
// Pass 1: online softmax stats per (head, row).
// ---------------------------------------------------------------------------
template <int HD>
__global__ __launch_bounds__(256) void attn_stats(
    const float* __restrict__ Q, const float* __restrict__ K,
    const float* __restrict__ aparam, int amode,
    float* __restrict__ mout, float* __restrict__ lout,
    int Tq, int Tk, int nh, float inv_scale)
{
    constexpr int ROWS = 64;
    constexpr int STILE = (HD == 64) ? 64 : 32;
    constexpr int CPT = STILE / 16;
    __shared__ float qs[ROWS][HD + 4];
    __shared__ float ks[STILE][HD + 4];
    __shared__ float redm[ROWS][17];
    __shared__ float redl[ROWS][17];

    const int tid = threadIdx.x;
    const int h = blockIdx.y;
    const int r0 = blockIdx.x * ROWS;
    const float ascale = head_alpha(aparam, amode, h) * inv_scale;

    for (int idx = tid; idx < ROWS * HD; idx += 256) {
        int r = idx / HD, d = idx % HD;
        qs[r][d] = Q[(size_t)(r0 + r) * D_MODEL + h * HD + d];
    }
    const int ty = tid >> 4, tx = tid & 15;
    float mreg[4] = {-1e30f, -1e30f, -1e30f, -1e30f};
    float lreg[4] = {0.f, 0.f, 0.f, 0.f};

    for (int s0 = 0; s0 < Tk; s0 += STILE) {
        __syncthreads();
        for (int idx = tid; idx < STILE * HD; idx += 256) {
            int r = idx / HD, d = idx % HD;
            ks[r][d] = K[(size_t)(s0 + r) * D_MODEL + h * HD + d];
        }
        __syncthreads();
        float sc[4][CPT];
#pragma unroll
        for (int i = 0; i < 4; ++i)
#pragma unroll
            for (int j = 0; j < CPT; ++j) sc[i][j] = 0.0f;

        for (int d0 = 0; d0 < HD; d0 += 4) {
            float4 bv[CPT];
#pragma unroll
            for (int j = 0; j < CPT; ++j) bv[j] = *(const float4*)&ks[tx * CPT + j][d0];
#pragma unroll
            for (int i = 0; i < 4; ++i) {
                float4 a = *(const float4*)&qs[ty * 4 + i][d0];
#pragma unroll
                for (int j = 0; j < CPT; ++j)
                    sc[i][j] += a.x * bv[j].x + a.y * bv[j].y + a.z * bv[j].z + a.w * bv[j].w;
            }
        }
#pragma unroll
        for (int i = 0; i < 4; ++i) {
            float tm = -1e30f;
#pragma unroll
            for (int j = 0; j < CPT; ++j) { sc[i][j] *= ascale; tm = fmaxf(tm, sc[i][j]); }
            float nm = fmaxf(mreg[i], tm);
            float add = 0.0f;
#pragma unroll
            for (int j = 0; j < CPT; ++j) add += __expf(sc[i][j] - nm);
            lreg[i] = lreg[i] * __expf(mreg[i] - nm) + add;
            mreg[i] = nm;
        }
    }
#pragma unroll
    for (int i = 0; i < 4; ++i) { redm[ty * 4 + i][tx] = mreg[i]; redl[ty * 4 + i][tx] = lreg[i]; }
    __syncthreads();
    if (tid < ROWS) {
        float mm = -1e30f, ll = 0.0f;
        for (int x = 0; x < 16; ++x) {
            float mx = redm[tid][x], lx = redl[tid][x];
            float nm = fmaxf(mm, mx);
            ll = ll * __expf(mm - nm) + lx * __expf(mx - nm);
            mm = nm;
        }
        mout[h * Tq + r0 + tid] = mm;
        lout[h * Tq + r0 + tid] = ll;
    }
}

// ---------------------------------------------------------------------------
// Pass 2: recompute p = exp(alpha*score - m)/l tile by tile.
//   - O[(r, h*HD+c)] += osc * sum_s p*V      (atomicAdd over col chunks)
//   - comb[r][c]     += (S/nh) * sum_h p     (exclusive chunk; S = s0+s1+s3)
// ---------------------------------------------------------------------------
template <int HD, bool COMB>
__global__ __launch_bounds__(256) void attn_apply(
    const float* __restrict__ Q, const float* __restrict__ K,
    const float* __restrict__ V,
    const float* __restrict__ mrow, const float* __restrict__ lrow,
    const float* __restrict__ aparam, int amode,
    float* __restrict__ O,
    const float* __restrict__ strat, int o_sidx,
    float* __restrict__ comb,
    int Tq, int Tk, int nh, float inv_scale)
{
    constexpr int ROWS = 32, STILE = 64, CS = 128;
    constexpr int PC = HD / 8;
    __shared__ float qs[ROWS][HD + 4];
    __shared__ float ks[STILE][HD + 4];
    __shared__ float ptile[ROWS][STILE + 1];
    __shared__ float combtile[COMB ? ROWS : 1][COMB ? CS : 4];
    __shared__ float m_s[ROWS], linv_s[ROWS];

    const int tid = threadIdx.x;
    const int r0 = blockIdx.x * ROWS;
    const int c0 = blockIdx.y * CS;

    if constexpr (COMB) {
        for (int i = tid; i < ROWS * CS; i += 256) (&combtile[0][0])[i] = 0.0f;
    }
    const int ty = tid >> 5;
    const int tx = tid & 31;
    const int pr = tid >> 3;
    const int pc0 = (tid & 7) * PC;

    for (int h = 0; h < nh; ++h) {
        for (int idx = tid; idx < ROWS * HD; idx += 256) {
            int r = idx / HD, d = idx % HD;
            qs[r][d] = Q[(size_t)(r0 + r) * D_MODEL + h * HD + d];
        }
        if (tid < ROWS) {
            m_s[tid] = mrow[h * Tq + r0 + tid];
            linv_s[tid] = 1.0f / lrow[h * Tq + r0 + tid];
        }
        const float ascale = head_alpha(aparam, amode, h) * inv_scale;

        float4 oacc[PC / 4];
#pragma unroll
        for (int j = 0; j < PC / 4; ++j) oacc[j] = make_float4(0.f, 0.f, 0.f, 0.f);

        __syncthreads();

        for (int s0 = c0; s0 < c0 + CS; s0 += STILE) {
            for (int idx = tid; idx < STILE * HD; idx += 256) {
                int r = idx / HD, d = idx % HD;
                ks[r][d] = K[(size_t)(s0 + r) * D_MODEL + h * HD + d];
            }
            __syncthreads();
            float sc[4][2] = {};
            for (int d0 = 0; d0 < HD; d0 += 4) {
                float4 b0 = *(const float4*)&ks[tx * 2][d0];
                float4 b1 = *(const float4*)&ks[tx * 2 + 1][d0];
#pragma unroll
                for (int i = 0; i < 4; ++i) {
                    float4 a = *(const float4*)&qs[ty * 4 + i][d0];
                    sc[i][0] += a.x * b0.x + a.y * b0.y + a.z * b0.z + a.w * b0.w;
                    sc[i][1] += a.x * b1.x + a.y * b1.y + a.z * b1.z + a.w * b1.w;
                }
            }
#pragma unroll
            for (int i = 0; i < 4; ++i) {
                const int rr = ty * 4 + i;
                const float mm = m_s[rr], li = linv_s[rr];
#pragma unroll
                for (int j = 0; j < 2; ++j) {
                    float p = __expf(sc[i][j] * ascale - mm) * li;
                    ptile[rr][tx * 2 + j] = p;
                    if constexpr (COMB) combtile[rr][(s0 - c0) + tx * 2 + j] += p;
                }
            }
            __syncthreads();
#pragma unroll 4
            for (int s = 0; s < STILE; ++s) {
                float pv = ptile[pr][s];
                const float4* vr = (const float4*)(V + (size_t)(s0 + s) * D_MODEL + h * HD + pc0);
#pragma unroll
                for (int j = 0; j < PC / 4; ++j) {
                    float4 v4 = vr[j];
                    oacc[j].x += pv * v4.x; oacc[j].y += pv * v4.y;
                    oacc[j].z += pv * v4.z; oacc[j].w += pv * v4.w;
                }
            }
            __syncthreads();
        }
        const float osc = (o_sidx >= 0) ? strat[o_sidx] : 1.0f;
        float* orow = O + (size_t)(r0 + pr) * D_MODEL + h * HD + pc0;
#pragma unroll
        for (int j = 0; j < PC / 4; ++j) {
            atomicAdd(orow + j * 4 + 0, osc * oacc[j].x);
            atomicAdd(orow + j * 4 + 1, osc * oacc[j].y);
            atomicAdd(orow + j * 4 + 2, osc * oacc[j].z);
            atomicAdd(orow + j * 4 + 3, osc * oacc[j].w);
        }
        __syncthreads();
    }
    if constexpr (COMB) {
        // combined plane scale: (strat[0]+strat[1]+strat[3]) / nh
        const float csc = (strat[0] + strat[1] + strat[3]) / (float)nh;
        for (int idx = tid; idx < ROWS * CS; idx += 256) {
            int r = idx / CS, c = idx % CS;
            size_t gi = (size_t)(r0 + r) * Tk + c0 + c;
            comb[gi] += csc * combtile[r][c];
        }
    }
}

// ---------------------------------------------------------------------------
// Per-head 64x64 rotation: Y[t][h*64+e] = sum_d X[t][h*64+d] * R[h][d][e]
// ---------------------------------------------------------------------------
__global__ __launch_bounds__(256) void rotate_heads(
    const float* __restrict__ X, const float* __restrict__ R,
    float* __restrict__ Y)
{
    __shared__ float Rt[64][68];
    __shared__ float xs[64][68];
    const int tid = threadIdx.x;
    const int h = blockIdx.y;
    const int t0 = blockIdx.x * 64;
    for (int idx = tid; idx < 4096; idx += 256) {
        int d = idx >> 6, e = idx & 63;
        Rt[e][d] = R[h * 4096 + idx];
        xs[d][e] = X[(size_t)(t0 + d) * D_MODEL + h * 64 + e];
    }
    __syncthreads();
    const int ty = tid >> 4, tx = tid & 15;
    float acc[4][4] = {};
    for (int d0 = 0; d0 < 64; d0 += 4) {
        float4 rv[4];
#pragma unroll
        for (int j = 0; j < 4; ++j) rv[j] = *(const float4*)&Rt[tx * 4 + j][d0];
#pragma unroll
        for (int i = 0; i < 4; ++i) {
            float4 a = *(const float4*)&xs[ty * 4 + i][d0];
#pragma unroll
            for (int j = 0; j < 4; ++j)
                acc[i][j] += a.x * rv[j].x + a.y * rv[j].y + a.z * rv[j].z + a.w * rv[j].w;
        }
    }
#pragma unroll
    for (int i = 0; i < 4; ++i)
#pragma unroll
        for (int j = 0; j < 4; ++j)
            Y[(size_t)(t0 + ty * 4 + i) * D_MODEL + h * 64 + tx * 4 + j] = acc[i][j];
}

// ---------------------------------------------------------------------------
// F.interpolate(mode='linear', align_corners=False): [256,1024] -> [2048,1024]
// ---------------------------------------------------------------------------
__global__ __launch_bounds__(256) void interp_lin(
    const float* __restrict__ G, float* __restrict__ out)
{
    const int t = blockIdx.x;
    float src = (t + 0.5f) * 0.125f - 0.5f;
    src = fminf(fmaxf(src, 0.0f), 255.0f);
    float fl = floorf(src);
    int i0 = (int)fl;
    int i1 = min(i0 + 1, 255);
    float w = src - fl;
    const float4* g0 = (const float4*)(G + (size_t)i0 * D_MODEL);
    const float4* g1 = (const float4*)(G + (size_t)i1 * D_MODEL);
    float4* o = (float4*)(out + (size_t)t * D_MODEL);
    int c = threadIdx.x;
    float4 a = g0[c], b = g1[c];
    float4 r;
    r.x = a.x * (1.0f - w) + b.x * w;
    r.y = a.y * (1.0f - w) + b.y * w;
    r.z = a.z * (1.0f - w) + b.z * w;
    r.w = a.w * (1.0f - w) + b.w * w;
    o[c] = r;
}

// ---------------------------------------------------------------------------
extern "C" void kernel_launch(void* const* d_in, const int* in_sizes, int n_in,
                              void* d_out, int out_size, void* d_ws, size_t ws_size,
                              hipStream_t stream)
{
    (void)in_sizes; (void)n_in; (void)ws_size;
    const float* query    = (const float*)d_in[0];
    const float* key      = (const float*)d_in[1];
    const float* value    = (const float*)d_in[2];
    const float* strat    = (const float*)d_in[3];
    const float* Wqkv_lin = (const float*)d_in[4];
    const float* b_lin    = (const float*)d_in[5];
    const float* Wo_lin   = (const float*)d_in[6];
    const float* bo_lin   = (const float*)d_in[7];
    const float* spars    = (const float*)d_in[8];
    const float* Wqkv_loc = (const float*)d_in[9];
    const float* b_loc    = (const float*)d_in[10];
    const float* Wo_loc   = (const float*)d_in[11];
    const float* bo_loc   = (const float*)d_in[12];
    const float* Wqkv_glb = (const float*)d_in[13];
    const float* b_glb    = (const float*)d_in[14];
    const float* Wo_glb   = (const float*)d_in[15];
    const float* bo_glb   = (const float*)d_in[16];
    const float* Wf       = (const float*)d_in[17];
    const float* bf       = (const float*)d_in[18];
    const float* Rq       = (const float*)d_in[19];
    const float* ent      = (const float*)d_in[20];

    float* out = (float*)d_out;
    float* weighted = out;                        // [2048][1024]
    float* combined = out + (size_t)2048 * 1024;  // [3][2048][2048] planes
    const size_t PLANE = (size_t)2048 * 2048;

    float* ws   = (float*)d_ws;
    float* qkv  = ws;                   // 3 x 2048x1024
    float* AO   = qkv + 6291456;
    float* LO   = AO + 2097152;
    float* gqkv = LO + 2097152;
    float* gAO  = gqkv + 786432;
    float* gOUT = gAO + 262144;
    float* GI   = gOUT + 262144;
    float* mb   = GI + 2097152;
    float* lb   = mb + 32768;
    float* qrot = qkv;                  // alias: lin qkv dead by then
    float* krot = qkv + 2097152;

    const float inv8   = 0.125f;
    const float inv128 = 1.0f / sqrtf(128.0f);
    const float* srcs[3] = {query, key, value};

    hipMemsetAsync(d_out, 0, (size_t)out_size * sizeof(float), stream);

    // ---- LINEAR (proj'd MHA, 16 heads; combined plane 0) ----
    for (int sl = 0; sl < 3; ++sl)
        gemm_xwt<<<dim3(32, 16), 256, 0, stream>>>(
            srcs[sl], 1024, Wqkv_lin + (size_t)sl * 1048576, 1024, b_lin + sl * 1024,
            qkv + (size_t)sl * 2097152, 2048, 1024, 1024, nullptr, 0, 0);
    attn_stats<64><<<dim3(32, 16), 256, 0, stream>>>(
        qkv, qkv + 2097152, nullptr, 0, mb, lb, 2048, 2048, 16, inv8);
    hipMemsetAsync(AO, 0, (size_t)2097152 * 4, stream);
    attn_apply<64, true><<<dim3(64, 16), 256, 0, stream>>>(
        qkv, qkv + 2097152, qkv + 4194304, mb, lb, nullptr, 0,
        AO, strat, -1, combined + 0 * PLANE, 2048, 2048, 16, inv8);
    gemm_xwt<<<dim3(32, 16), 256, 0, stream>>>(
        AO, 1024, Wo_lin, 1024, bo_lin, weighted, 2048, 1024, 1024, strat, 0, 1);

    // ---- SPARSE (raw heads, mask per head; combined plane 1) ----
    attn_stats<64><<<dim3(32, 16), 256, 0, stream>>>(
        query, key, spars, 1, mb, lb, 2048, 2048, 16, inv8);
    attn_apply<64, true><<<dim3(64, 16), 256, 0, stream>>>(
        query, key, value, mb, lb, spars, 1,
        weighted, strat, 1, combined + 1 * PLANE, 2048, 2048, 16, inv8);

    // ---- QUANTUM (rotated raw heads, gate per head; combined plane 2) ----
    rotate_heads<<<dim3(32, 16), 256, 0, stream>>>(query, Rq, qrot);
    rotate_heads<<<dim3(32, 16), 256, 0, stream>>>(key, Rq, krot);
    attn_stats<64><<<dim3(32, 16), 256, 0, stream>>>(
        qrot, krot, ent, 2, mb, lb, 2048, 2048, 16, inv8);
    attn_apply<64, true><<<dim3(64, 16), 256, 0, stream>>>(
        qrot, krot, value, mb, lb, ent, 2,
        weighted, strat, 3, combined + 2 * PLANE, 2048, 2048, 16, inv8);

    // ---- LOCAL (proj'd MHA, 8 heads x 128) ----
    for (int sl = 0; sl < 3; ++sl)
        gemm_xwt<<<dim3(32, 16), 256, 0, stream>>>(
            srcs[sl], 1024, Wqkv_loc + (size_t)sl * 1048576, 1024, b_loc + sl * 1024,
            qkv + (size_t)sl * 2097152, 2048, 1024, 1024, nullptr, 0, 0);
    attn_stats<128><<<dim3(32, 8), 256, 0, stream>>>(
        qkv, qkv + 2097152, nullptr, 0, mb, lb, 2048, 2048, 8, inv128);
    hipMemsetAsync(AO, 0, (size_t)2097152 * 4, stream);
    attn_apply<128, false><<<dim3(64, 16), 256, 0, stream>>>(
        qkv, qkv + 2097152, qkv + 4194304, mb, lb, nullptr, 0,
        AO, strat, -1, nullptr, 2048, 2048, 8, inv128);
    gemm_xwt<<<dim3(32, 16), 256, 0, stream>>>(
        AO, 1024, Wo_loc, 1024, bo_loc, LO, 2048, 1024, 1024, nullptr, 0, 0);

    // ---- GLOBAL (strided pool to 256 tokens, 8 heads x 128, interp back) ----
    for (int sl = 0; sl < 3; ++sl)
        gemm_xwt<<<dim3(4, 16), 256, 0, stream>>>(
            srcs[sl], 8192, Wqkv_glb + (size_t)sl * 1048576, 1024, b_glb + sl * 1024,
            gqkv + (size_t)sl * 262144, 256, 1024, 1024, nullptr, 0, 0);
    attn_stats<128><<<dim3(4, 8), 256, 0, stream>>>(
        gqkv, gqkv + 262144, nullptr, 0, mb, lb, 256, 256, 8, inv128);
    hipMemsetAsync(gAO, 0, (size_t)262144 * 4, stream);
    attn_apply<128, false><<<dim3(8, 2), 256, 0, stream>>>(
        gqkv, gqkv + 262144, gqkv + 524288, mb, lb, nullptr, 0,
        gAO, strat, -1, nullptr, 256, 256, 8, inv128);
    gemm_xwt<<<dim3(4, 16), 256, 0, stream>>>(
        gAO, 1024, Wo_glb, 1024, bo_glb, gOUT, 256, 1024, 1024, nullptr, 0, 0);
    interp_lin<<<dim3(2048), 256, 0, stream>>>(gOUT, GI);

    // ---- HIER: weighted += sp2 * (LO @ WfL^T + GI @ WfR^T + bf) ----
    gemm_xwt<<<dim3(32, 16), 256, 0, stream>>>(
        LO, 1024, Wf, 2048, bf, weighted, 2048, 1024, 1024, strat, 2, 1);
    gemm_xwt<<<dim3(32, 16), 256, 0, stream>>>(
        GI, 1024, Wf + 1024, 2048, nullptr, weighted, 2048, 1024, 1024, strat, 2, 1);
}